// Round 1
// 4532.993 us; speedup vs baseline: 4.4370x; 4.4370x over previous
//
#include <hip/hip_runtime.h>
#include <hip/hip_bf16.h>
#include <math.h>

typedef __hip_bfloat16 bf16;
typedef __attribute__((ext_vector_type(8))) short short8;
typedef __attribute__((ext_vector_type(4))) float float4v;

#define Bb   4
#define Ss   512
#define Dd   768
#define Hh   12
#define Ll   12
#define Ff   3072
#define DHh  64
#define Pp   512
#define BSs  (Bb*Ss)
#define BHh  (Bb*Hh)
#define MRo  2560              // 2048 h-rows + 512 rel rows

// adaptive float load: isb=1 -> buffer is bf16, isb=0 -> fp32
__device__ __forceinline__ float ldf(const void* p, long i, int isb){
  return isb ? __bfloat162float(((const bf16*)p)[i]) : ((const float*)p)[i];
}

// dtype sniff: attention_mask is all ones. packed bf16 ones = 0x3F803F80.
__global__ void sniff_kernel(const unsigned* __restrict__ mask_raw, int* __restrict__ flag){
  if (threadIdx.x == 0 && blockIdx.x == 0)
    *flag = (mask_raw[0] == 0x3F803F80u) ? 1 : 0;
}

// ---------------- reductions (256-thread block = 4 waves) ----------------
__device__ __forceinline__ float wave_sum(float v){
  #pragma unroll
  for (int o = 32; o > 0; o >>= 1) v += __shfl_down(v, o, 64);
  return v;
}
__device__ __forceinline__ float wave_max(float v){
  #pragma unroll
  for (int o = 32; o > 0; o >>= 1) v = fmaxf(v, __shfl_down(v, o, 64));
  return v;
}
__device__ __forceinline__ float block_sum(float v, float* red){
  v = wave_sum(v);
  if ((threadIdx.x & 63) == 0) red[threadIdx.x >> 6] = v;
  __syncthreads();
  float r = red[0] + red[1] + red[2] + red[3];
  __syncthreads();
  return r;
}
__device__ __forceinline__ float block_max(float v, float* red){
  v = wave_max(v);
  if ((threadIdx.x & 63) == 0) red[threadIdx.x >> 6] = v;
  __syncthreads();
  float r = fmaxf(fmaxf(red[0], red[1]), fmaxf(red[2], red[3]));
  __syncthreads();
  return r;
}

// =====================================================================
// MFMA bf16 GEMM:  C[z] = A[z] @ B[z]^T(+bias)   (B stored [N,K], k-contig)
// BM=FM*32, BN=FN*32, BK=64. 4 waves in 2x2, wave tile (FM*16)x(FN*16)*? ->
// each wave owns (FM*16*2? no): wave (wm,wn) owns FMx FN 16x16 fragments.
// LDS tiles swizzled: stored 16B-chunk c of row r holds logical chunk c^(r&7)
// (source-address pre-swizzle so global_load_lds stays linear-dest).
// EPI: 0 none, 1 +bias, 2 +bias+gelu.  OUT: 0 f32, 1 bf16.
// =====================================================================
template<int FM,int FN,int EPI,int OUT>
__global__ __launch_bounds__(256)
void mgemm_kernel(const bf16* __restrict__ A, const bf16* __restrict__ Bm,
                  void* __restrict__ Cout, const float* __restrict__ bias,
                  int K, int lda, int ldb, int ldc,
                  long sA, long sB, long sC, int sbias)
{
  constexpr int BM = FM*32, BN = FN*32;
  __shared__ __align__(16) bf16 As[BM*64];
  __shared__ __align__(16) bf16 Bs[BN*64];

  const int z = blockIdx.z;
  A  += (long)z * sA;
  Bm += (long)z * sB;
  const long cbase = (long)z * sC;

  const int tid  = threadIdx.x;
  const int wid  = tid >> 6, lane = tid & 63;
  const int wm   = wid >> 1, wn  = wid & 1;
  const int l15  = lane & 15, l4 = lane >> 4;
  const int row0 = blockIdx.y * BM, col0 = blockIdx.x * BN;

  float4v acc[FM][FN];
  #pragma unroll
  for (int i = 0; i < FM; i++)
    #pragma unroll
    for (int j = 0; j < FN; j++)
      #pragma unroll
      for (int q = 0; q < 4; q++) acc[i][j][q] = 0.f;

  for (int k0 = 0; k0 < K; k0 += 64) {
    // ---- stage A tile [BM][64] (swizzled source, linear LDS dest) ----
    #pragma unroll
    for (int i = 0; i < FM; i++) {
      int byteoff = i*4096 + tid*16;
      int r  = byteoff >> 7;           // tile row (rows are 64 bf16 = 128 B)
      int c  = (byteoff >> 4) & 7;     // stored 16B chunk
      int kc = c ^ (r & 7);            // logical k-chunk
      const bf16* src = A + (long)(row0 + r)*lda + (k0 + kc*8);
      __builtin_amdgcn_global_load_lds(
          (const __attribute__((address_space(1))) void*)src,
          (__attribute__((address_space(3))) void*)(As + i*2048 + wid*512),
          16, 0, 0);
    }
    // ---- stage B tile [BN][64] ----
    #pragma unroll
    for (int i = 0; i < FN; i++) {
      int byteoff = i*4096 + tid*16;
      int r  = byteoff >> 7;
      int c  = (byteoff >> 4) & 7;
      int kc = c ^ (r & 7);
      const bf16* src = Bm + (long)(col0 + r)*ldb + (k0 + kc*8);
      __builtin_amdgcn_global_load_lds(
          (const __attribute__((address_space(1))) void*)src,
          (__attribute__((address_space(3))) void*)(Bs + i*2048 + wid*512),
          16, 0, 0);
    }
    __syncthreads();

    #pragma unroll
    for (int s = 0; s < 2; s++) {
      short8 af[FM], bfr[FN];
      #pragma unroll
      for (int m = 0; m < FM; m++) {
        int r  = wm*(FM*16) + m*16 + l15;
        int kc = (s*4 + l4) ^ (r & 7);
        af[m] = *(const short8*)(As + r*64 + kc*8);
      }
      #pragma unroll
      for (int n = 0; n < FN; n++) {
        int r  = wn*(FN*16) + n*16 + l15;
        int kc = (s*4 + l4) ^ (r & 7);
        bfr[n] = *(const short8*)(Bs + r*64 + kc*8);
      }
      #pragma unroll
      for (int m = 0; m < FM; m++)
        #pragma unroll
        for (int n = 0; n < FN; n++)
          acc[m][n] = __builtin_amdgcn_mfma_f32_16x16x32_bf16(af[m], bfr[n], acc[m][n], 0, 0, 0);
    }
    __syncthreads();
  }

  // ---- epilogue: C row=(l>>4)*4+reg, col=lane&15 (m89-verified) ----
  float* Cf = (float*)Cout;
  bf16*  Cb = (bf16*)Cout;
  #pragma unroll
  for (int m = 0; m < FM; m++) {
    int rr = row0 + wm*(FM*16) + m*16 + l4*4;
    #pragma unroll
    for (int n = 0; n < FN; n++) {
      int cc = col0 + wn*(FN*16) + n*16 + l15;
      float bv = 0.f;
      if constexpr (EPI >= 1) bv = bias[(long)z*sbias + cc];
      #pragma unroll
      for (int j = 0; j < 4; j++) {
        float v = acc[m][n][j] + bv;
        if constexpr (EPI == 2) v = 0.5f*v*(1.0f + erff(v*0.70710678118654752f));
        long idx = cbase + (long)(rr + j)*ldc + cc;
        if constexpr (OUT == 0) Cf[idx] = v;
        else                    Cb[idx] = __float2bfloat16(v);
      }
    }
  }
}

// ---------------- weight transpose-convert: W[K,N](raw) -> WT[N,K] bf16 ----
// blockIdx.z picks among up to 3 source weight arrays (same K,N,woff).
__global__ __launch_bounds__(256)
void wtrans_kernel(const void* __restrict__ W0, const void* __restrict__ W1p,
                   const void* __restrict__ W2p, bf16* __restrict__ WT,
                   int Kd, int Nd, long woff, const int* __restrict__ flag)
{
  const int isb = *flag;
  const void* W = blockIdx.z == 0 ? W0 : (blockIdx.z == 1 ? W1p : W2p);
  bf16* T = WT + (long)blockIdx.z * Kd * Nd;
  __shared__ float s[64][65];
  const int n0 = blockIdx.x*64, k0 = blockIdx.y*64;
  const int tc = (threadIdx.x & 15)*4;
  const int tr = threadIdx.x >> 4;
  #pragma unroll
  for (int i = 0; i < 4; i++) {
    int kk = tr + i*16;
    long base = woff + (long)(k0 + kk)*Nd + n0 + tc;
    #pragma unroll
    for (int j = 0; j < 4; j++) s[kk][tc + j] = ldf(W, base + j, isb);
  }
  __syncthreads();
  #pragma unroll
  for (int i = 0; i < 4; i++) {
    int nn = tr + i*16;
    long base = (long)(n0 + nn)*Kd + k0 + tc;
    #pragma unroll
    for (int j = 0; j < 4; j++) T[base + j] = __float2bfloat16(s[tc + j][nn]);
  }
}

// ---------------- V transpose: vb[2048,768] -> vbT[b,h,dh,s] bf16 ----------
__global__ __launch_bounds__(256)
void vtrans_kernel(const bf16* __restrict__ vb, bf16* __restrict__ vbT)
{
  __shared__ float s[64][65];
  const int s0 = blockIdx.x*64, hh = blockIdx.y, b = blockIdx.z;
  const bf16* src = vb + (long)b*Ss*Dd + hh*DHh;
  bf16* dst = vbT + ((long)(b*Hh + hh)*DHh)*Ss;
  const int tc = (threadIdx.x & 15)*4;
  const int tr = threadIdx.x >> 4;
  #pragma unroll
  for (int i = 0; i < 4; i++) {
    int row = tr + i*16;   // s index
    long base = (long)(s0 + row)*Dd + tc;
    #pragma unroll
    for (int j = 0; j < 4; j++) s[row][tc + j] = __bfloat162float(src[base + j]);
  }
  __syncthreads();
  #pragma unroll
  for (int i = 0; i < 4; i++) {
    int dh = tr + i*16;
    long base = (long)dh*Ss + s0 + tc;
    #pragma unroll
    for (int j = 0; j < 4; j++) dst[base + j] = __float2bfloat16(s[tc + j][dh]);
  }
}

// ---------------- embedding + LN + mask (writes f32 h and bf16 mirror) ----
__global__ __launch_bounds__(256)
void embed_ln_kernel(const int* __restrict__ ids, const int* __restrict__ segs,
                     const int* __restrict__ pins, const void* __restrict__ mask,
                     const void* __restrict__ tok, const void* __restrict__ pin,
                     const void* __restrict__ seg, const void* __restrict__ lnw,
                     const void* __restrict__ lnb, float* __restrict__ h,
                     bf16* __restrict__ hb, float* __restrict__ maskadd,
                     const int* __restrict__ flag)
{
  __shared__ float red[4];
  const int isb = *flag;
  int t = blockIdx.x;
  long to = (long)ids[t]*Dd, po = (long)pins[t]*Dd, so = (long)segs[t]*Dd;
  float e[3]; float s = 0.f;
  #pragma unroll
  for (int i = 0; i < 3; i++) {
    int d = threadIdx.x + i*256;
    e[i] = ldf(tok, to+d, isb) + ldf(pin, po+d, isb) + ldf(seg, so+d, isb);
    s += e[i];
  }
  float mu = block_sum(s, red) * (1.0f/Dd);
  float vs = 0.f;
  #pragma unroll
  for (int i = 0; i < 3; i++) { float d0 = e[i]-mu; vs += d0*d0; }
  float var = block_sum(vs, red) * (1.0f/Dd);
  float inv = 1.0f / sqrtf(var + 1e-12f);
  float mv = ldf(mask, t, isb);
  #pragma unroll
  for (int i = 0; i < 3; i++) {
    int d = threadIdx.x + i*256;
    float v = ((e[i]-mu)*inv*ldf(lnw, d, isb) + ldf(lnb, d, isb)) * mv;
    h[(long)t*Dd + d]  = v;
    hb[(long)t*Dd + d] = __float2bfloat16(v);
  }
  if (threadIdx.x == 0) maskadd[t] = (1.0f - mv) * (-1e9f);
}

// ---------------- residual add + LN (f32 h in place + bf16 mirror) --------
__global__ __launch_bounds__(256)
void add_ln_kernel(float* __restrict__ h, const float* __restrict__ addv,
                   const void* __restrict__ w, const void* __restrict__ b,
                   long off, const int* __restrict__ flag, bf16* __restrict__ hb)
{
  __shared__ float red[4];
  const int isb = *flag;
  int t = blockIdx.x;
  float e[3]; float s = 0.f;
  #pragma unroll
  for (int i = 0; i < 3; i++) {
    int d = threadIdx.x + i*256;
    e[i] = h[(long)t*Dd + d] + addv[(long)t*Dd + d];
    s += e[i];
  }
  float mu = block_sum(s, red) * (1.0f/Dd);
  float vs = 0.f;
  #pragma unroll
  for (int i = 0; i < 3; i++) { float d0 = e[i]-mu; vs += d0*d0; }
  float var = block_sum(vs, red) * (1.0f/Dd);
  float inv = 1.0f / sqrtf(var + 1e-12f);
  #pragma unroll
  for (int i = 0; i < 3; i++) {
    int d = threadIdx.x + i*256;
    float v = (e[i]-mu)*inv*ldf(w, off+d, isb) + ldf(b, off+d, isb);
    h[(long)t*Dd + d]  = v;
    hb[(long)t*Dd + d] = __float2bfloat16(v);
  }
}

// ---------------- DeBERTa-v2 log-bucket relative position indices ---------
__global__ void relidx_kernel(int* __restrict__ cidx, int* __restrict__ pidx)
{
  int idx = blockIdx.x*256 + threadIdx.x;
  if (idx >= Ss*Ss) return;
  int r = idx / Ss, c = idx % Ss;
  int rel = r - c;
  const int mid = 128;
  int sgn = (rel > 0) - (rel < 0);
  int abs_pos = (rel < mid && rel > -mid) ? (mid - 1) : abs(rel);
  int bucket;
  if (abs_pos <= mid) bucket = rel;
  else {
    double lp = ceil(log((double)abs_pos / (double)mid) / log(511.0/128.0) * (double)(mid-1)) + (double)mid;
    bucket = (int)(lp * (double)sgn);
  }
  int ci = bucket + 256;  ci = ci < 0 ? 0 : (ci > 511 ? 511 : ci);
  int pi = -bucket + 256; pi = pi < 0 ? 0 : (pi > 511 ? 511 : pi);
  cidx[idx] = ci;
  pidx[idx] = pi;
}

// ------- qk + c2p/p2c gathers + mask + softmax; probs written bf16 in place
__global__ __launch_bounds__(256)
void attn_softmax_kernel(float* __restrict__ score, const float* __restrict__ c2p,
                         const float* __restrict__ p2c, const int* __restrict__ cidx,
                         const int* __restrict__ pidx, const float* __restrict__ maskadd)
{
  __shared__ float red[4];
  const float SCALE = 0.07216878364870322f;   // 1/sqrt(64*3)
  int q = blockIdx.x;
  int hd = blockIdx.y;
  float* row = score + ((long)hd*Ss + q)*Ss;
  const float* c2pr = c2p + (long)hd*Ss*Pp + (long)q*Pp;
  const float* p2cm = p2c + (long)hd*Ss*Pp;
  float v[2];
  #pragma unroll
  for (int i = 0; i < 2; i++) {
    int k = threadIdx.x + i*256;
    float sv = row[k] + c2pr[cidx[q*Ss + k]] + p2cm[(long)k*Pp + pidx[k*Ss + q]];
    v[i] = sv * SCALE + maskadd[k];
  }
  float mx = block_max(fmaxf(v[0], v[1]), red);
  float e0 = __expf(v[0] - mx), e1 = __expf(v[1] - mx);
  float inv = 1.0f / block_sum(e0 + e1, red);
  // all reads of this row completed before the barriers above; reuse as bf16
  bf16* rowb = (bf16*)row;
  rowb[threadIdx.x]       = __float2bfloat16(e0 * inv);
  rowb[threadIdx.x + 256] = __float2bfloat16(e1 * inv);
}

// ---------------- converts ----------------
__global__ void cvt_in_kernel(const void* __restrict__ in, float* __restrict__ out,
                              const int* __restrict__ flag, int n){
  int i = blockIdx.x*256 + threadIdx.x;
  if (i < n) out[i] = ldf(in, i, *flag);
}
__global__ void cvt_bf16_kernel(const void* __restrict__ in, bf16* __restrict__ out,
                                const int* __restrict__ flag, int n){
  int i = blockIdx.x*256 + threadIdx.x;
  if (i < n) out[i] = __float2bfloat16(ldf(in, i, *flag));
}
__global__ void store_out_kernel(const float* __restrict__ in, void* __restrict__ out,
                                 const int* __restrict__ flag, int n){
  int i = blockIdx.x*256 + threadIdx.x;
  if (i < n) {
    if (*flag) ((bf16*)out)[i] = __float2bfloat16(in[i]);
    else       ((float*)out)[i] = in[i];
  }
}

extern "C" void kernel_launch(void* const* d_in, const int* in_sizes, int n_in,
                              void* d_out, int out_size, void* d_ws, size_t ws_size,
                              hipStream_t stream)
{
  const int*  input_ids   = (const int*) d_in[0];
  const int*  segment_ids = (const int*) d_in[1];
  const int*  pinyin_ids  = (const int*) d_in[2];
  const void* attn_mask   = d_in[3];
  const void* tok_emb     = d_in[4];
  const void* pin_emb     = d_in[5];
  const void* seg_emb     = d_in[6];
  const void* emb_ln_w    = d_in[7];
  const void* emb_ln_b    = d_in[8];
  const void* rel_emb     = d_in[9];
  const void* Wq = d_in[10]; const void* bq = d_in[11];
  const void* Wk = d_in[12]; const void* bk = d_in[13];
  const void* Wv = d_in[14]; const void* bv = d_in[15];
  const void* Wo = d_in[16]; const void* bo = d_in[17];
  const void* ln1w = d_in[18]; const void* ln1b = d_in[19];
  const void* W1 = d_in[20]; const void* b1 = d_in[21];
  const void* W2 = d_in[22]; const void* b2 = d_in[23];
  const void* ln2w = d_in[24]; const void* ln2b = d_in[25];

  // ---- workspace layout, ~79.5 MB total ----
  float* ws    = (float*)d_ws;
  float* h     = ws;                               // 2048*768 f32
  float* tmp   = h    + (long)BSs*Dd;              // 2048*768 f32
  float* scr   = tmp  + (long)BSs*Dd;              // 12*512*512 f32 (scores/probs)
  float* c2pb  = scr  + (long)Hh*Ss*Ss;            // 12*512*512 f32
  float* p2cb  = c2pb + (long)Hh*Ss*Pp;            // 12*512*512 f32
  float* madd  = p2cb + (long)Hh*Ss*Pp;            // 2048
  float* biasb = madd + BSs;                       // 82944 f32 (all biases)
  int*   cidx  = (int*)(biasb + 82944);            // 512*512
  int*   pidx  = cidx + Ss*Ss;
  int*   dflag = pidx + Ss*Ss;                     // 64 ints
  bf16*  hrel  = (bf16*)(dflag + 64);              // [2560][768]: h rows + rel rows
  bf16*  qkvc  = hrel + (long)MRo*Dd;              // [3][2560][768]
  bf16*  ctxb  = qkvc + (long)3*MRo*Dd;            // [2048][768]
  bf16*  vbT   = ctxb + (long)BSs*Dd;              // [4*12*64][512]
  bf16*  WTb   = vbT  + (long)BHh*DHh*Ss;          // up to 3072*768 (or 3*768*768)
  bf16*  ffb   = (bf16*)c2pb;                      // alias: [2048][3072] bf16 in FFN phase

  const bf16* posqb = qkvc + (long)BSs*Dd;                      // z=0 slab rows 2048+
  const bf16* poskb = qkvc + (long)MRo*Dd + (long)BSs*Dd;       // z=1 slab rows 2048+
  const bf16* vbs   = qkvc + (long)2*MRo*Dd;                    // z=2 slab rows 0..2047

  sniff_kernel<<<1, 64, 0, stream>>>((const unsigned*)attn_mask, dflag);
  relidx_kernel<<<(Ss*Ss + 255)/256, 256, 0, stream>>>(cidx, pidx);
  cvt_bf16_kernel<<<(Pp*Dd + 255)/256, 256, 0, stream>>>(rel_emb, hrel + (long)BSs*Dd, dflag, Pp*Dd);
  embed_ln_kernel<<<BSs, 256, 0, stream>>>(input_ids, segment_ids, pinyin_ids, attn_mask,
                                           tok_emb, pin_emb, seg_emb, emb_ln_w, emb_ln_b,
                                           h, hrel, madd, dflag);
  // biases -> f32, all layers at once. layout: bq@0 bk@9216 bv@18432 bo@27648 b1@36864 b2@73728
  int nb = Ll*Dd;
  cvt_in_kernel<<<(nb+255)/256, 256, 0, stream>>>(bq, biasb,         dflag, nb);
  cvt_in_kernel<<<(nb+255)/256, 256, 0, stream>>>(bk, biasb + 9216,  dflag, nb);
  cvt_in_kernel<<<(nb+255)/256, 256, 0, stream>>>(bv, biasb + 18432, dflag, nb);
  cvt_in_kernel<<<(nb+255)/256, 256, 0, stream>>>(bo, biasb + 27648, dflag, nb);
  cvt_in_kernel<<<(Ll*Ff+255)/256, 256, 0, stream>>>(b1, biasb + 36864, dflag, Ll*Ff);
  cvt_in_kernel<<<(nb+255)/256, 256, 0, stream>>>(b2, biasb + 73728, dflag, nb);

  for (int l = 0; l < Ll; l++) {
    long oW  = (long)l*Dd*Dd, oW1 = (long)l*Dd*Ff, oW2 = (long)l*Ff*Dd;

    // ---- Wq,Wk,Wv -> WTb [3][768][768] bf16 (transposed) ----
    wtrans_kernel<<<dim3(12,12,3), 256, 0, stream>>>(Wq, Wk, Wv, WTb, Dd, Dd, oW, dflag);
    // ---- fused QKV + pos projections: A=[h||rel] (2560 rows), z = q/k/v ----
    mgemm_kernel<4,4,1,1><<<dim3(Dd/128, MRo/128, 3), 256, 0, stream>>>(
        hrel, WTb, qkvc, biasb + (long)l*Dd,
        Dd, Dd, Dd, Dd, 0L, (long)Dd*Dd, (long)MRo*Dd, 9216);
    // ---- V -> vbT[b,h,dh,s] ----
    vtrans_kernel<<<dim3(Ss/64, Hh, Bb), 256, 0, stream>>>(vbs, vbT);

    for (int b = 0; b < Bb; b++) {
      const bf16* qbb = qkvc + (long)b*Ss*Dd;
      const bf16* kbb = qkvc + (long)MRo*Dd + (long)b*Ss*Dd;
      // scores = Q @ K^T (per head, z=h, head col offset 64*h)
      mgemm_kernel<2,2,0,0><<<dim3(Ss/64, Ss/64, Hh), 256, 0, stream>>>(
          qbb, kbb, scr, nullptr, DHh, Dd, Dd, Ss, 64L, 64L, (long)Ss*Ss, 0);
      // c2p = Q @ pos_k^T
      mgemm_kernel<2,2,0,0><<<dim3(Pp/64, Ss/64, Hh), 256, 0, stream>>>(
          qbb, poskb, c2pb, nullptr, DHh, Dd, Dd, Pp, 64L, 64L, (long)Ss*Pp, 0);
      // p2c = K @ pos_q^T
      mgemm_kernel<2,2,0,0><<<dim3(Pp/64, Ss/64, Hh), 256, 0, stream>>>(
          kbb, posqb, p2cb, nullptr, DHh, Dd, Dd, Pp, 64L, 64L, (long)Ss*Pp, 0);
      attn_softmax_kernel<<<dim3(Ss,Hh), 256, 0, stream>>>(scr, c2pb, p2cb, cidx, pidx,
                                                           madd + (long)b*Ss);
      // ctx = probs(bf16, in place over scr, row stride 1024) @ V^T(vbT)
      mgemm_kernel<2,2,0,1><<<dim3(1, Ss/64, Hh), 256, 0, stream>>>(
          (const bf16*)scr, vbT + (long)b*Hh*DHh*Ss, ctxb + (long)b*Ss*Dd, nullptr,
          Ss, 2*Ss, Ss, Dd, (long)Ss*2*Ss, (long)DHh*Ss, 64L, 0);
    }

    // ---- Wo ----
    wtrans_kernel<<<dim3(12,12,1), 256, 0, stream>>>(Wo, Wo, Wo, WTb, Dd, Dd, oW, dflag);
    mgemm_kernel<2,2,1,0><<<dim3(Dd/64, BSs/64, 1), 256, 0, stream>>>(
        ctxb, WTb, tmp, biasb + 27648 + (long)l*Dd, Dd, Dd, Dd, Dd, 0L, 0L, 0L, 0);
    add_ln_kernel<<<BSs, 256, 0, stream>>>(h, tmp, ln1w, ln1b, (long)l*Dd, dflag, hrel);

    // ---- FFN ----
    wtrans_kernel<<<dim3(Ff/64, Dd/64, 1), 256, 0, stream>>>(W1, W1, W1, WTb, Dd, Ff, oW1, dflag);
    mgemm_kernel<4,4,2,1><<<dim3(Ff/128, BSs/128, 1), 256, 0, stream>>>(
        hrel, WTb, ffb, biasb + 36864 + (long)l*Ff, Dd, Dd, Dd, Ff, 0L, 0L, 0L, 0);
    wtrans_kernel<<<dim3(Dd/64, Ff/64, 1), 256, 0, stream>>>(W2, W2, W2, WTb, Ff, Dd, oW2, dflag);
    mgemm_kernel<2,2,1,0><<<dim3(Dd/64, BSs/64, 1), 256, 0, stream>>>(
        ffb, WTb, tmp, biasb + 73728 + (long)l*Dd, Ff, Ff, Ff, Dd, 0L, 0L, 0L, 0);
    add_ln_kernel<<<BSs, 256, 0, stream>>>(h, tmp, ln2w, ln2b, (long)l*Dd, dflag, hrel);
  }

  store_out_kernel<<<(BSs*Dd + 255)/256, 256, 0, stream>>>(h, d_out, dflag, BSs*Dd);
}

// Round 2
// 3782.010 us; speedup vs baseline: 5.3180x; 1.1986x over previous
//
#include <hip/hip_runtime.h>
#include <hip/hip_bf16.h>
#include <math.h>

typedef __hip_bfloat16 bf16;
typedef __attribute__((ext_vector_type(8))) short short8;
typedef __attribute__((ext_vector_type(4))) float float4v;

#define Bb   4
#define Ss   512
#define Dd   768
#define Hh   12
#define Ll   12
#define Ff   3072
#define DHh  64
#define Pp   512
#define BSs  (Bb*Ss)
#define BHh  (Bb*Hh)
#define MRo  2560              // 2048 h-rows + 512 rel rows

// adaptive float load: isb=1 -> buffer is bf16, isb=0 -> fp32
__device__ __forceinline__ float ldf(const void* p, long i, int isb){
  return isb ? __bfloat162float(((const bf16*)p)[i]) : ((const float*)p)[i];
}

// dtype sniff: attention_mask is all ones. packed bf16 ones = 0x3F803F80.
__global__ void sniff_kernel(const unsigned* __restrict__ mask_raw, int* __restrict__ flag){
  if (threadIdx.x == 0 && blockIdx.x == 0)
    *flag = (mask_raw[0] == 0x3F803F80u) ? 1 : 0;
}

// ---------------- reductions (256-thread block = 4 waves) ----------------
__device__ __forceinline__ float wave_sum(float v){
  #pragma unroll
  for (int o = 32; o > 0; o >>= 1) v += __shfl_down(v, o, 64);
  return v;
}
__device__ __forceinline__ float wave_max(float v){
  #pragma unroll
  for (int o = 32; o > 0; o >>= 1) v = fmaxf(v, __shfl_down(v, o, 64));
  return v;
}
__device__ __forceinline__ float block_sum(float v, float* red){
  v = wave_sum(v);
  if ((threadIdx.x & 63) == 0) red[threadIdx.x >> 6] = v;
  __syncthreads();
  float r = red[0] + red[1] + red[2] + red[3];
  __syncthreads();
  return r;
}
__device__ __forceinline__ float block_max(float v, float* red){
  v = wave_max(v);
  if ((threadIdx.x & 63) == 0) red[threadIdx.x >> 6] = v;
  __syncthreads();
  float r = fmaxf(fmaxf(red[0], red[1]), fmaxf(red[2], red[3]));
  __syncthreads();
  return r;
}

// =====================================================================
// MFMA bf16 GEMM:  C[z] = A[z] @ B[z]^T(+bias)   (B stored [N,K], k-contig)
// LDS tiles swizzled: stored 16B-chunk c of row r holds logical chunk c^(r&7)
// (source-address pre-swizzle so global_load_lds stays linear-dest).
// EPI: 0 none, 1 +bias, 2 +bias+gelu.  OUT: 0 f32, 1 bf16.
// ZM:  0 plain (C += z*sC), 2 PV decode (C += (z/Hh)*Ss*Dd + (z%Hh)*DHh).
// =====================================================================
template<int FM,int FN,int EPI,int OUT,int ZM=0>
__global__ __launch_bounds__(256)
void mgemm_kernel(const bf16* __restrict__ A, const bf16* __restrict__ Bm,
                  void* __restrict__ Cout, const float* __restrict__ bias,
                  int K, int lda, int ldb, int ldc,
                  long sA, long sB, long sC, int sbias)
{
  constexpr int BM = FM*32, BN = FN*32;
  __shared__ __align__(16) bf16 As[BM*64];
  __shared__ __align__(16) bf16 Bs[BN*64];

  const int z = blockIdx.z;
  A  += (long)z * sA;
  Bm += (long)z * sB;
  long cbase;
  if constexpr (ZM == 2) cbase = (long)(z/Hh)*((long)Ss*Dd) + (long)(z%Hh)*DHh;
  else                   cbase = (long)z * sC;

  const int tid  = threadIdx.x;
  const int wid  = tid >> 6, lane = tid & 63;
  const int wm   = wid >> 1, wn  = wid & 1;
  const int l15  = lane & 15, l4 = lane >> 4;
  const int row0 = blockIdx.y * BM, col0 = blockIdx.x * BN;

  float4v acc[FM][FN];
  #pragma unroll
  for (int i = 0; i < FM; i++)
    #pragma unroll
    for (int j = 0; j < FN; j++)
      #pragma unroll
      for (int q = 0; q < 4; q++) acc[i][j][q] = 0.f;

  for (int k0 = 0; k0 < K; k0 += 64) {
    // ---- stage A tile [BM][64] (swizzled source, linear LDS dest) ----
    #pragma unroll
    for (int i = 0; i < FM; i++) {
      int byteoff = i*4096 + tid*16;
      int r  = byteoff >> 7;           // tile row (rows are 64 bf16 = 128 B)
      int c  = (byteoff >> 4) & 7;     // stored 16B chunk
      int kc = c ^ (r & 7);            // logical k-chunk
      const bf16* src = A + (long)(row0 + r)*lda + (k0 + kc*8);
      __builtin_amdgcn_global_load_lds(
          (const __attribute__((address_space(1))) void*)src,
          (__attribute__((address_space(3))) void*)(As + i*2048 + wid*512),
          16, 0, 0);
    }
    // ---- stage B tile [BN][64] ----
    #pragma unroll
    for (int i = 0; i < FN; i++) {
      int byteoff = i*4096 + tid*16;
      int r  = byteoff >> 7;
      int c  = (byteoff >> 4) & 7;
      int kc = c ^ (r & 7);
      const bf16* src = Bm + (long)(col0 + r)*ldb + (k0 + kc*8);
      __builtin_amdgcn_global_load_lds(
          (const __attribute__((address_space(1))) void*)src,
          (__attribute__((address_space(3))) void*)(Bs + i*2048 + wid*512),
          16, 0, 0);
    }
    __syncthreads();

    #pragma unroll
    for (int s = 0; s < 2; s++) {
      short8 af[FM], bfr[FN];
      #pragma unroll
      for (int m = 0; m < FM; m++) {
        int r  = wm*(FM*16) + m*16 + l15;
        int kc = (s*4 + l4) ^ (r & 7);
        af[m] = *(const short8*)(As + r*64 + kc*8);
      }
      #pragma unroll
      for (int n = 0; n < FN; n++) {
        int r  = wn*(FN*16) + n*16 + l15;
        int kc = (s*4 + l4) ^ (r & 7);
        bfr[n] = *(const short8*)(Bs + r*64 + kc*8);
      }
      #pragma unroll
      for (int m = 0; m < FM; m++)
        #pragma unroll
        for (int n = 0; n < FN; n++)
          acc[m][n] = __builtin_amdgcn_mfma_f32_16x16x32_bf16(af[m], bfr[n], acc[m][n], 0, 0, 0);
    }
    __syncthreads();
  }

  // ---- epilogue: C row=(l>>4)*4+reg, col=lane&15 (m89-verified) ----
  float* Cf = (float*)Cout;
  bf16*  Cb = (bf16*)Cout;
  #pragma unroll
  for (int m = 0; m < FM; m++) {
    int rr = row0 + wm*(FM*16) + m*16 + l4*4;
    #pragma unroll
    for (int n = 0; n < FN; n++) {
      int cc = col0 + wn*(FN*16) + n*16 + l15;
      float bv = 0.f;
      if constexpr (EPI >= 1) bv = bias[(long)z*sbias + cc];
      #pragma unroll
      for (int j = 0; j < 4; j++) {
        float v = acc[m][n][j] + bv;
        if constexpr (EPI == 2) v = 0.5f*v*(1.0f + erff(v*0.70710678118654752f));
        long idx = cbase + (long)(rr + j)*ldc + cc;
        if constexpr (OUT == 0) Cf[idx] = v;
        else                    Cb[idx] = __float2bfloat16(v);
      }
    }
  }
}

// =====================================================================
// Batched attention score GEMMs: z = kind*nbh + bh, bh = b*Hh + h.
// kind 0: scr = Q @ K^T      kind 1: c2p = Q @ posk^T   kind 2: p2c = K @ posq^T
// All M=N=512, K=64, 64x64 tiles. bOffA: extra batch offset (per-batch mode).
// =====================================================================
__global__ __launch_bounds__(256)
void scores_kernel(const bf16* __restrict__ qkvc, float* __restrict__ scr,
                   float* __restrict__ c2p, float* __restrict__ p2c,
                   int nbh, long bOffA)
{
  __shared__ __align__(16) bf16 As[64*64];
  __shared__ __align__(16) bf16 Bs[64*64];

  const int z = blockIdx.z;
  const int kind = z / nbh, bh = z - kind*nbh;
  const int b = bh / Hh, hh = bh - b*Hh;
  const long qoff = bOffA + (long)b*Ss*Dd + (long)hh*DHh;

  const bf16* A; const bf16* Bm; float* C;
  if (kind == 0) {
    A = qkvc + qoff;                       // Q rows
    Bm = qkvc + (long)MRo*Dd + qoff;       // K rows
    C = scr + (long)bh*Ss*Ss;
  } else if (kind == 1) {
    A = qkvc + qoff;                                         // Q rows
    Bm = qkvc + (long)MRo*Dd + (long)BSs*Dd + (long)hh*DHh;  // pos_k
    C = c2p + (long)bh*Ss*Pp;
  } else {
    A = qkvc + (long)MRo*Dd + qoff;                          // K rows
    Bm = qkvc + (long)BSs*Dd + (long)hh*DHh;                 // pos_q
    C = p2c + (long)bh*Ss*Pp;
  }

  const int tid = threadIdx.x;
  const int wid = tid >> 6, lane = tid & 63;
  const int wm = wid >> 1, wn = wid & 1;
  const int l15 = lane & 15, l4 = lane >> 4;
  const int row0 = blockIdx.y * 64, col0 = blockIdx.x * 64;

  #pragma unroll
  for (int i = 0; i < 2; i++) {
    int byteoff = i*4096 + tid*16;
    int r  = byteoff >> 7;
    int c  = (byteoff >> 4) & 7;
    int kc = c ^ (r & 7);
    __builtin_amdgcn_global_load_lds(
        (const __attribute__((address_space(1))) void*)(A + (long)(row0 + r)*Dd + kc*8),
        (__attribute__((address_space(3))) void*)(As + i*2048 + wid*512), 16, 0, 0);
    __builtin_amdgcn_global_load_lds(
        (const __attribute__((address_space(1))) void*)(Bm + (long)(col0 + r)*Dd + kc*8),
        (__attribute__((address_space(3))) void*)(Bs + i*2048 + wid*512), 16, 0, 0);
  }
  __syncthreads();

  float4v acc[2][2];
  #pragma unroll
  for (int i = 0; i < 2; i++)
    #pragma unroll
    for (int j = 0; j < 2; j++)
      #pragma unroll
      for (int q = 0; q < 4; q++) acc[i][j][q] = 0.f;

  #pragma unroll
  for (int s = 0; s < 2; s++) {
    short8 af[2], bfr[2];
    #pragma unroll
    for (int m = 0; m < 2; m++) {
      int r  = wm*32 + m*16 + l15;
      int kc = (s*4 + l4) ^ (r & 7);
      af[m] = *(const short8*)(As + r*64 + kc*8);
    }
    #pragma unroll
    for (int n = 0; n < 2; n++) {
      int r  = wn*32 + n*16 + l15;
      int kc = (s*4 + l4) ^ (r & 7);
      bfr[n] = *(const short8*)(Bs + r*64 + kc*8);
    }
    #pragma unroll
    for (int m = 0; m < 2; m++)
      #pragma unroll
      for (int n = 0; n < 2; n++)
        acc[m][n] = __builtin_amdgcn_mfma_f32_16x16x32_bf16(af[m], bfr[n], acc[m][n], 0, 0, 0);
  }

  #pragma unroll
  for (int m = 0; m < 2; m++) {
    int rr = row0 + wm*32 + m*16 + l4*4;
    #pragma unroll
    for (int n = 0; n < 2; n++) {
      int cc = col0 + wn*32 + n*16 + l15;
      #pragma unroll
      for (int j = 0; j < 4; j++)
        C[(long)(rr + j)*512 + cc] = acc[m][n][j];
    }
  }
}

// ---------------- weight transpose-convert: W[K,N](raw) -> WT[N,K] bf16 ----
__global__ __launch_bounds__(256)
void wtrans_kernel(const void* __restrict__ W0, const void* __restrict__ W1p,
                   const void* __restrict__ W2p, bf16* __restrict__ WT,
                   int Kd, int Nd, long woff, const int* __restrict__ flag)
{
  const int isb = *flag;
  const void* W = blockIdx.z == 0 ? W0 : (blockIdx.z == 1 ? W1p : W2p);
  bf16* T = WT + (long)blockIdx.z * Kd * Nd;
  __shared__ float s[64][65];
  const int n0 = blockIdx.x*64, k0 = blockIdx.y*64;
  const int tc = (threadIdx.x & 15)*4;
  const int tr = threadIdx.x >> 4;
  #pragma unroll
  for (int i = 0; i < 4; i++) {
    int kk = tr + i*16;
    long base = woff + (long)(k0 + kk)*Nd + n0 + tc;
    #pragma unroll
    for (int j = 0; j < 4; j++) s[kk][tc + j] = ldf(W, base + j, isb);
  }
  __syncthreads();
  #pragma unroll
  for (int i = 0; i < 4; i++) {
    int nn = tr + i*16;
    long base = (long)(n0 + nn)*Kd + k0 + tc;
    #pragma unroll
    for (int j = 0; j < 4; j++) T[base + j] = __float2bfloat16(s[tc + j][nn]);
  }
}

// ---------------- V transpose: vb[2048,768] -> vbT[b,h,dh,s] bf16 ----------
__global__ __launch_bounds__(256)
void vtrans_kernel(const bf16* __restrict__ vb, bf16* __restrict__ vbT)
{
  __shared__ float s[64][65];
  const int s0 = blockIdx.x*64, hh = blockIdx.y, b = blockIdx.z;
  const bf16* src = vb + (long)b*Ss*Dd + hh*DHh;
  bf16* dst = vbT + ((long)(b*Hh + hh)*DHh)*Ss;
  const int tc = (threadIdx.x & 15)*4;
  const int tr = threadIdx.x >> 4;
  #pragma unroll
  for (int i = 0; i < 4; i++) {
    int row = tr + i*16;   // s index
    long base = (long)(s0 + row)*Dd + tc;
    #pragma unroll
    for (int j = 0; j < 4; j++) s[row][tc + j] = __bfloat162float(src[base + j]);
  }
  __syncthreads();
  #pragma unroll
  for (int i = 0; i < 4; i++) {
    int dh = tr + i*16;
    long base = (long)dh*Ss + s0 + tc;
    #pragma unroll
    for (int j = 0; j < 4; j++) dst[base + j] = __float2bfloat16(s[tc + j][dh]);
  }
}

// ---------------- embedding + LN + mask (writes f32 h and bf16 mirror) ----
__global__ __launch_bounds__(256)
void embed_ln_kernel(const int* __restrict__ ids, const int* __restrict__ segs,
                     const int* __restrict__ pins, const void* __restrict__ mask,
                     const void* __restrict__ tok, const void* __restrict__ pin,
                     const void* __restrict__ seg, const void* __restrict__ lnw,
                     const void* __restrict__ lnb, float* __restrict__ h,
                     bf16* __restrict__ hb, float* __restrict__ maskadd,
                     const int* __restrict__ flag)
{
  __shared__ float red[4];
  const int isb = *flag;
  int t = blockIdx.x;
  long to = (long)ids[t]*Dd, po = (long)pins[t]*Dd, so = (long)segs[t]*Dd;
  float e[3]; float s = 0.f;
  #pragma unroll
  for (int i = 0; i < 3; i++) {
    int d = threadIdx.x + i*256;
    e[i] = ldf(tok, to+d, isb) + ldf(pin, po+d, isb) + ldf(seg, so+d, isb);
    s += e[i];
  }
  float mu = block_sum(s, red) * (1.0f/Dd);
  float vs = 0.f;
  #pragma unroll
  for (int i = 0; i < 3; i++) { float d0 = e[i]-mu; vs += d0*d0; }
  float var = block_sum(vs, red) * (1.0f/Dd);
  float inv = 1.0f / sqrtf(var + 1e-12f);
  float mv = ldf(mask, t, isb);
  #pragma unroll
  for (int i = 0; i < 3; i++) {
    int d = threadIdx.x + i*256;
    float v = ((e[i]-mu)*inv*ldf(lnw, d, isb) + ldf(lnb, d, isb)) * mv;
    h[(long)t*Dd + d]  = v;
    hb[(long)t*Dd + d] = __float2bfloat16(v);
  }
  if (threadIdx.x == 0) maskadd[t] = (1.0f - mv) * (-1e9f);
}

// ---------------- residual add + LN (f32 h in place + bf16 mirror) --------
__global__ __launch_bounds__(256)
void add_ln_kernel(float* __restrict__ h, const float* __restrict__ addv,
                   const void* __restrict__ w, const void* __restrict__ b,
                   long off, const int* __restrict__ flag, bf16* __restrict__ hb)
{
  __shared__ float red[4];
  const int isb = *flag;
  int t = blockIdx.x;
  float e[3]; float s = 0.f;
  #pragma unroll
  for (int i = 0; i < 3; i++) {
    int d = threadIdx.x + i*256;
    e[i] = h[(long)t*Dd + d] + addv[(long)t*Dd + d];
    s += e[i];
  }
  float mu = block_sum(s, red) * (1.0f/Dd);
  float vs = 0.f;
  #pragma unroll
  for (int i = 0; i < 3; i++) { float d0 = e[i]-mu; vs += d0*d0; }
  float var = block_sum(vs, red) * (1.0f/Dd);
  float inv = 1.0f / sqrtf(var + 1e-12f);
  #pragma unroll
  for (int i = 0; i < 3; i++) {
    int d = threadIdx.x + i*256;
    float v = (e[i]-mu)*inv*ldf(w, off+d, isb) + ldf(b, off+d, isb);
    h[(long)t*Dd + d]  = v;
    hb[(long)t*Dd + d] = __float2bfloat16(v);
  }
}

// ---------------- DeBERTa-v2 log-bucket relative position indices ---------
__global__ void relidx_kernel(int* __restrict__ cidx, int* __restrict__ pidx)
{
  int idx = blockIdx.x*256 + threadIdx.x;
  if (idx >= Ss*Ss) return;
  int r = idx / Ss, c = idx % Ss;
  int rel = r - c;
  const int mid = 128;
  int sgn = (rel > 0) - (rel < 0);
  int abs_pos = (rel < mid && rel > -mid) ? (mid - 1) : abs(rel);
  int bucket;
  if (abs_pos <= mid) bucket = rel;
  else {
    double lp = ceil(log((double)abs_pos / (double)mid) / log(511.0/128.0) * (double)(mid-1)) + (double)mid;
    bucket = (int)(lp * (double)sgn);
  }
  int ci = bucket + 256;  ci = ci < 0 ? 0 : (ci > 511 ? 511 : ci);
  int pi = -bucket + 256; pi = pi < 0 ? 0 : (pi > 511 ? 511 : pi);
  cidx[idx] = ci;
  pidx[idx] = pi;
}

// ------- qk + c2p/p2c gathers + mask + softmax; probs written bf16 in place
// grid (Ss, nbh); slice bh = blockIdx.y, batch b = bh/Hh (for mask rows).
__global__ __launch_bounds__(256)
void attn_softmax_kernel(float* __restrict__ score, const float* __restrict__ c2p,
                         const float* __restrict__ p2c, const int* __restrict__ cidx,
                         const int* __restrict__ pidx, const float* __restrict__ maskadd)
{
  __shared__ float red[4];
  const float SCALE = 0.07216878364870322f;   // 1/sqrt(64*3)
  int q = blockIdx.x;
  int bh = blockIdx.y;
  int b = bh / Hh;
  float* row = score + ((long)bh*Ss + q)*Ss;
  const float* c2pr = c2p + (long)bh*Ss*Pp + (long)q*Pp;
  const float* p2cm = p2c + (long)bh*Ss*Pp;
  float v[2];
  #pragma unroll
  for (int i = 0; i < 2; i++) {
    int k = threadIdx.x + i*256;
    float sv = row[k] + c2pr[cidx[q*Ss + k]] + p2cm[(long)k*Pp + pidx[k*Ss + q]];
    v[i] = sv * SCALE + maskadd[b*Ss + k];
  }
  float mx = block_max(fmaxf(v[0], v[1]), red);
  float e0 = __expf(v[0] - mx), e1 = __expf(v[1] - mx);
  float inv = 1.0f / block_sum(e0 + e1, red);
  // all reads of this row completed before the barriers above; reuse as bf16
  bf16* rowb = (bf16*)row;
  rowb[threadIdx.x]       = __float2bfloat16(e0 * inv);
  rowb[threadIdx.x + 256] = __float2bfloat16(e1 * inv);
}

// ---------------- converts ----------------
__global__ void cvt_in_kernel(const void* __restrict__ in, float* __restrict__ out,
                              const int* __restrict__ flag, int n){
  int i = blockIdx.x*256 + threadIdx.x;
  if (i < n) out[i] = ldf(in, i, *flag);
}
__global__ void cvt_bf16_kernel(const void* __restrict__ in, bf16* __restrict__ out,
                                const int* __restrict__ flag, int n){
  int i = blockIdx.x*256 + threadIdx.x;
  if (i < n) out[i] = __float2bfloat16(ldf(in, i, *flag));
}
__global__ void store_out_kernel(const float* __restrict__ in, void* __restrict__ out,
                                 const int* __restrict__ flag, int n){
  int i = blockIdx.x*256 + threadIdx.x;
  if (i < n) {
    if (*flag) ((bf16*)out)[i] = __float2bfloat16(in[i]);
    else       ((float*)out)[i] = in[i];
  }
}

extern "C" void kernel_launch(void* const* d_in, const int* in_sizes, int n_in,
                              void* d_out, int out_size, void* d_ws, size_t ws_size,
                              hipStream_t stream)
{
  const int*  input_ids   = (const int*) d_in[0];
  const int*  segment_ids = (const int*) d_in[1];
  const int*  pinyin_ids  = (const int*) d_in[2];
  const void* attn_mask   = d_in[3];
  const void* tok_emb     = d_in[4];
  const void* pin_emb     = d_in[5];
  const void* seg_emb     = d_in[6];
  const void* emb_ln_w    = d_in[7];
  const void* emb_ln_b    = d_in[8];
  const void* rel_emb     = d_in[9];
  const void* Wq = d_in[10]; const void* bq = d_in[11];
  const void* Wk = d_in[12]; const void* bk = d_in[13];
  const void* Wv = d_in[14]; const void* bv = d_in[15];
  const void* Wo = d_in[16]; const void* bo = d_in[17];
  const void* ln1w = d_in[18]; const void* ln1b = d_in[19];
  const void* W1 = d_in[20]; const void* b1 = d_in[21];
  const void* W2 = d_in[22]; const void* b2 = d_in[23];
  const void* ln2w = d_in[24]; const void* ln2b = d_in[25];

  // ---- workspace layout. Full tier (~184 MB) batches scores across all
  // (b,h); falls back to per-batch (~80 MB, proven to fit) otherwise. ----
  float *h, *tmp, *scr, *c2pb, *p2cb, *madd, *biasb;
  int *cidx, *pidx, *dflag;
  bf16 *hrel, *qkvc, *ctxb, *vbT, *WTb;
  auto build = [&](int nb_) -> size_t {
    float* ws = (float*)d_ws;
    h     = ws;
    tmp   = h    + (long)BSs*Dd;
    scr   = tmp  + (long)BSs*Dd;
    c2pb  = scr  + (long)nb_*Hh*Ss*Ss;
    p2cb  = c2pb + (long)nb_*Hh*Ss*Pp;
    madd  = p2cb + (long)nb_*Hh*Ss*Pp;
    biasb = madd + BSs;
    cidx  = (int*)(biasb + 82944);
    pidx  = cidx + Ss*Ss;
    dflag = pidx + Ss*Ss;
    hrel  = (bf16*)(dflag + 64);
    qkvc  = hrel + (long)MRo*Dd;
    ctxb  = qkvc + 3L*MRo*Dd;
    vbT   = ctxb + (long)BSs*Dd;
    WTb   = vbT  + (long)BHh*DHh*Ss;
    bf16* end = WTb + (long)Ff*Dd;
    return (size_t)((char*)end - (char*)d_ws);
  };
  int nb = Bb;
  if (build(Bb) > ws_size) { nb = 1; build(1); }
  const int nbh = nb * Hh;
  bf16* ffb = (bf16*)scr;   // alias: scores region dead during FFN

  const bf16* posqb = qkvc + (long)BSs*Dd;                      // z=0 slab rows 2048+
  const bf16* poskb = qkvc + (long)MRo*Dd + (long)BSs*Dd;       // z=1 slab rows 2048+
  const bf16* vbs   = qkvc + (long)2*MRo*Dd;                    // z=2 slab rows 0..2047

  sniff_kernel<<<1, 64, 0, stream>>>((const unsigned*)attn_mask, dflag);
  relidx_kernel<<<(Ss*Ss + 255)/256, 256, 0, stream>>>(cidx, pidx);
  cvt_bf16_kernel<<<(Pp*Dd + 255)/256, 256, 0, stream>>>(rel_emb, hrel + (long)BSs*Dd, dflag, Pp*Dd);
  embed_ln_kernel<<<BSs, 256, 0, stream>>>(input_ids, segment_ids, pinyin_ids, attn_mask,
                                           tok_emb, pin_emb, seg_emb, emb_ln_w, emb_ln_b,
                                           h, hrel, madd, dflag);
  // biases -> f32: bq@0 bk@9216 bv@18432 bo@27648 b1@36864 b2@73728
  int nbia = Ll*Dd;
  cvt_in_kernel<<<(nbia+255)/256, 256, 0, stream>>>(bq, biasb,         dflag, nbia);
  cvt_in_kernel<<<(nbia+255)/256, 256, 0, stream>>>(bk, biasb + 9216,  dflag, nbia);
  cvt_in_kernel<<<(nbia+255)/256, 256, 0, stream>>>(bv, biasb + 18432, dflag, nbia);
  cvt_in_kernel<<<(nbia+255)/256, 256, 0, stream>>>(bo, biasb + 27648, dflag, nbia);
  cvt_in_kernel<<<(Ll*Ff+255)/256, 256, 0, stream>>>(b1, biasb + 36864, dflag, Ll*Ff);
  cvt_in_kernel<<<(nbia+255)/256, 256, 0, stream>>>(b2, biasb + 73728, dflag, nbia);

  for (int l = 0; l < Ll; l++) {
    long oW  = (long)l*Dd*Dd, oW1 = (long)l*Dd*Ff, oW2 = (long)l*Ff*Dd;

    // ---- Wq,Wk,Wv -> WTb [3][768][768] bf16 (transposed) ----
    wtrans_kernel<<<dim3(12,12,3), 256, 0, stream>>>(Wq, Wk, Wv, WTb, Dd, Dd, oW, dflag);
    // ---- fused QKV + pos projections: A=[h||rel] (2560 rows), z = q/k/v ----
    mgemm_kernel<4,4,1,1><<<dim3(Dd/128, MRo/128, 3), 256, 0, stream>>>(
        hrel, WTb, qkvc, biasb + (long)l*Dd,
        Dd, Dd, Dd, Dd, 0L, (long)Dd*Dd, (long)MRo*Dd, 9216);
    // ---- V -> vbT[b,h,dh,s] ----
    vtrans_kernel<<<dim3(Ss/64, Hh, Bb), 256, 0, stream>>>(vbs, vbT);

    if (nb == Bb) {
      // -------- fully batched attention: 3 launches --------
      scores_kernel<<<dim3(Ss/64, Ss/64, 3*nbh), 256, 0, stream>>>(
          qkvc, scr, c2pb, p2cb, nbh, 0L);
      attn_softmax_kernel<<<dim3(Ss, nbh), 256, 0, stream>>>(scr, c2pb, p2cb,
                                                             cidx, pidx, madd);
      mgemm_kernel<2,2,0,1,2><<<dim3(1, Ss/64, nbh), 256, 0, stream>>>(
          (const bf16*)scr, vbT, ctxb, nullptr,
          Ss, 2*Ss, Ss, Dd, (long)Ss*Ss*2, (long)DHh*Ss, 0L, 0);
    } else {
      // -------- per-batch fallback (~80 MB workspace) --------
      for (int b = 0; b < Bb; b++) {
        scores_kernel<<<dim3(Ss/64, Ss/64, 3*nbh), 256, 0, stream>>>(
            qkvc, scr, c2pb, p2cb, nbh, (long)b*Ss*Dd);
        attn_softmax_kernel<<<dim3(Ss, nbh), 256, 0, stream>>>(scr, c2pb, p2cb,
                                                               cidx, pidx, madd + (long)b*Ss);
        mgemm_kernel<2,2,0,1,2><<<dim3(1, Ss/64, nbh), 256, 0, stream>>>(
            (const bf16*)scr, vbT + (long)b*Hh*DHh*Ss, ctxb + (long)b*Ss*Dd, nullptr,
            Ss, 2*Ss, Ss, Dd, (long)Ss*Ss*2, (long)DHh*Ss, 0L, 0);
      }
    }

    // ---- Wo ----
    wtrans_kernel<<<dim3(12,12,1), 256, 0, stream>>>(Wo, Wo, Wo, WTb, Dd, Dd, oW, dflag);
    mgemm_kernel<2,2,1,0><<<dim3(Dd/64, BSs/64, 1), 256, 0, stream>>>(
        ctxb, WTb, tmp, biasb + 27648 + (long)l*Dd, Dd, Dd, Dd, Dd, 0L, 0L, 0L, 0);
    add_ln_kernel<<<BSs, 256, 0, stream>>>(h, tmp, ln1w, ln1b, (long)l*Dd, dflag, hrel);

    // ---- FFN ----
    wtrans_kernel<<<dim3(Ff/64, Dd/64, 1), 256, 0, stream>>>(W1, W1, W1, WTb, Dd, Ff, oW1, dflag);
    mgemm_kernel<4,4,2,1><<<dim3(Ff/128, BSs/128, 1), 256, 0, stream>>>(
        hrel, WTb, ffb, biasb + 36864 + (long)l*Ff, Dd, Dd, Dd, Ff, 0L, 0L, 0L, 0);
    wtrans_kernel<<<dim3(Dd/64, Ff/64, 1), 256, 0, stream>>>(W2, W2, W2, WTb, Ff, Dd, oW2, dflag);
    mgemm_kernel<2,2,1,0><<<dim3(Dd/64, BSs/64, 1), 256, 0, stream>>>(
        ffb, WTb, tmp, biasb + 73728 + (long)l*Dd, Ff, Ff, Ff, Dd, 0L, 0L, 0L, 0);
    add_ln_kernel<<<BSs, 256, 0, stream>>>(h, tmp, ln2w, ln2b, (long)l*Dd, dflag, hrel);
  }

  store_out_kernel<<<(BSs*Dd + 255)/256, 256, 0, stream>>>(h, d_out, dflag, BSs*Dd);
}

// Round 3
// 2563.127 us; speedup vs baseline: 7.8470x; 1.4755x over previous
//
#include <hip/hip_runtime.h>
#include <hip/hip_bf16.h>
#include <math.h>

typedef __hip_bfloat16 bf16;
typedef __attribute__((ext_vector_type(8))) short short8;
typedef __attribute__((ext_vector_type(4))) float float4v;

#define Bb   4
#define Ss   512
#define Dd   768
#define Hh   12
#define Ll   12
#define Ff   3072
#define DHh  64
#define Pp   512
#define BSs  (Bb*Ss)
#define BHh  (Bb*Hh)
#define MRo  2560              // 2048 h-rows + 512 rel rows

// adaptive float load: isb=1 -> buffer is bf16, isb=0 -> fp32
__device__ __forceinline__ float ldf(const void* p, long i, int isb){
  return isb ? __bfloat162float(((const bf16*)p)[i]) : ((const float*)p)[i];
}

// dtype sniff: attention_mask is all ones. packed bf16 ones = 0x3F803F80.
__global__ void sniff_kernel(const unsigned* __restrict__ mask_raw, int* __restrict__ flag){
  if (threadIdx.x == 0 && blockIdx.x == 0)
    *flag = (mask_raw[0] == 0x3F803F80u) ? 1 : 0;
}

// ---------------- reductions (256-thread block = 4 waves) ----------------
__device__ __forceinline__ float wave_sum(float v){
  #pragma unroll
  for (int o = 32; o > 0; o >>= 1) v += __shfl_down(v, o, 64);
  return v;
}
__device__ __forceinline__ float block_sum(float v, float* red){
  v = wave_sum(v);
  if ((threadIdx.x & 63) == 0) red[threadIdx.x >> 6] = v;
  __syncthreads();
  float r = red[0] + red[1] + red[2] + red[3];
  __syncthreads();
  return r;
}

// =====================================================================
// MFMA bf16 GEMM:  C[z] = A[z] @ B[z]^T(+bias)   (B stored [N,K], k-contig)
// LDS tiles swizzled: stored 16B-chunk c of row r holds logical chunk c^(r&7)
// (source-address pre-swizzle so global_load_lds stays linear-dest).
// EPI: 0 none, 1 +bias, 2 +bias+gelu.  OUT: 0 f32, 1 bf16.
// =====================================================================
template<int FM,int FN,int EPI,int OUT>
__global__ __launch_bounds__(256)
void mgemm_kernel(const bf16* __restrict__ A, const bf16* __restrict__ Bm,
                  void* __restrict__ Cout, const float* __restrict__ bias,
                  int K, int lda, int ldb, int ldc,
                  long sA, long sB, long sC, int sbias)
{
  constexpr int BM = FM*32, BN = FN*32;
  __shared__ __align__(16) bf16 As[BM*64];
  __shared__ __align__(16) bf16 Bs[BN*64];

  const int z = blockIdx.z;
  A  += (long)z * sA;
  Bm += (long)z * sB;
  const long cbase = (long)z * sC;

  const int tid  = threadIdx.x;
  const int wid  = tid >> 6, lane = tid & 63;
  const int wm   = wid >> 1, wn  = wid & 1;
  const int l15  = lane & 15, l4 = lane >> 4;
  const int row0 = blockIdx.y * BM, col0 = blockIdx.x * BN;

  float4v acc[FM][FN];
  #pragma unroll
  for (int i = 0; i < FM; i++)
    #pragma unroll
    for (int j = 0; j < FN; j++)
      #pragma unroll
      for (int q = 0; q < 4; q++) acc[i][j][q] = 0.f;

  for (int k0 = 0; k0 < K; k0 += 64) {
    #pragma unroll
    for (int i = 0; i < FM; i++) {
      int byteoff = i*4096 + tid*16;
      int r  = byteoff >> 7;
      int c  = (byteoff >> 4) & 7;
      int kc = c ^ (r & 7);
      const bf16* src = A + (long)(row0 + r)*lda + (k0 + kc*8);
      __builtin_amdgcn_global_load_lds(
          (const __attribute__((address_space(1))) void*)src,
          (__attribute__((address_space(3))) void*)(As + i*2048 + wid*512),
          16, 0, 0);
    }
    #pragma unroll
    for (int i = 0; i < FN; i++) {
      int byteoff = i*4096 + tid*16;
      int r  = byteoff >> 7;
      int c  = (byteoff >> 4) & 7;
      int kc = c ^ (r & 7);
      const bf16* src = Bm + (long)(col0 + r)*ldb + (k0 + kc*8);
      __builtin_amdgcn_global_load_lds(
          (const __attribute__((address_space(1))) void*)src,
          (__attribute__((address_space(3))) void*)(Bs + i*2048 + wid*512),
          16, 0, 0);
    }
    __syncthreads();

    #pragma unroll
    for (int s = 0; s < 2; s++) {
      short8 af[FM], bfr[FN];
      #pragma unroll
      for (int m = 0; m < FM; m++) {
        int r  = wm*(FM*16) + m*16 + l15;
        int kc = (s*4 + l4) ^ (r & 7);
        af[m] = *(const short8*)(As + r*64 + kc*8);
      }
      #pragma unroll
      for (int n = 0; n < FN; n++) {
        int r  = wn*(FN*16) + n*16 + l15;
        int kc = (s*4 + l4) ^ (r & 7);
        bfr[n] = *(const short8*)(Bs + r*64 + kc*8);
      }
      #pragma unroll
      for (int m = 0; m < FM; m++)
        #pragma unroll
        for (int n = 0; n < FN; n++)
          acc[m][n] = __builtin_amdgcn_mfma_f32_16x16x32_bf16(af[m], bfr[n], acc[m][n], 0, 0, 0);
    }
    __syncthreads();
  }

  float* Cf = (float*)Cout;
  bf16*  Cb = (bf16*)Cout;
  #pragma unroll
  for (int m = 0; m < FM; m++) {
    int rr = row0 + wm*(FM*16) + m*16 + l4*4;
    #pragma unroll
    for (int n = 0; n < FN; n++) {
      int cc = col0 + wn*(FN*16) + n*16 + l15;
      float bv = 0.f;
      if constexpr (EPI >= 1) bv = bias[(long)z*sbias + cc];
      #pragma unroll
      for (int j = 0; j < 4; j++) {
        float v = acc[m][n][j] + bv;
        if constexpr (EPI == 2) v = 0.5f*v*(1.0f + erff(v*0.70710678118654752f));
        long idx = cbase + (long)(rr + j)*ldc + cc;
        if constexpr (OUT == 0) Cf[idx] = v;
        else                    Cb[idx] = __float2bfloat16(v);
      }
    }
  }
}

// =====================================================================
// Positional score GEMMs, bf16 out: z = kind*nbh + bh.
// kind 0: c2p = Q @ posk^T     kind 1: p2c = K @ posq^T
// M=N=512, K=64, 64x64 tiles.
// =====================================================================
__global__ __launch_bounds__(256)
void scores_kernel(const bf16* __restrict__ qkvc, bf16* __restrict__ c2p,
                   bf16* __restrict__ p2c, int nbh, long bOffA)
{
  __shared__ __align__(16) bf16 As[64*64];
  __shared__ __align__(16) bf16 Bs[64*64];

  const int z = blockIdx.z;
  const int kind = z / nbh, bh = z - kind*nbh;
  const int b = bh / Hh, hh = bh - b*Hh;
  const long qoff = bOffA + (long)b*Ss*Dd + (long)hh*DHh;

  const bf16* A; const bf16* Bm; bf16* C;
  if (kind == 0) {
    A = qkvc + qoff;                                         // Q rows
    Bm = qkvc + (long)MRo*Dd + (long)BSs*Dd + (long)hh*DHh;  // pos_k
    C = c2p + (long)bh*Ss*Pp;
  } else {
    A = qkvc + (long)MRo*Dd + qoff;                          // K rows
    Bm = qkvc + (long)BSs*Dd + (long)hh*DHh;                 // pos_q
    C = p2c + (long)bh*Ss*Pp;
  }

  const int tid = threadIdx.x;
  const int wid = tid >> 6, lane = tid & 63;
  const int wm = wid >> 1, wn = wid & 1;
  const int l15 = lane & 15, l4 = lane >> 4;
  const int row0 = blockIdx.y * 64, col0 = blockIdx.x * 64;

  #pragma unroll
  for (int i = 0; i < 2; i++) {
    int byteoff = i*4096 + tid*16;
    int r  = byteoff >> 7;
    int c  = (byteoff >> 4) & 7;
    int kc = c ^ (r & 7);
    __builtin_amdgcn_global_load_lds(
        (const __attribute__((address_space(1))) void*)(A + (long)(row0 + r)*Dd + kc*8),
        (__attribute__((address_space(3))) void*)(As + i*2048 + wid*512), 16, 0, 0);
    __builtin_amdgcn_global_load_lds(
        (const __attribute__((address_space(1))) void*)(Bm + (long)(col0 + r)*Dd + kc*8),
        (__attribute__((address_space(3))) void*)(Bs + i*2048 + wid*512), 16, 0, 0);
  }
  __syncthreads();

  float4v acc[2][2];
  #pragma unroll
  for (int i = 0; i < 2; i++)
    #pragma unroll
    for (int j = 0; j < 2; j++)
      #pragma unroll
      for (int q = 0; q < 4; q++) acc[i][j][q] = 0.f;

  #pragma unroll
  for (int s = 0; s < 2; s++) {
    short8 af[2], bfr[2];
    #pragma unroll
    for (int m = 0; m < 2; m++) {
      int r  = wm*32 + m*16 + l15;
      int kc = (s*4 + l4) ^ (r & 7);
      af[m] = *(const short8*)(As + r*64 + kc*8);
    }
    #pragma unroll
    for (int n = 0; n < 2; n++) {
      int r  = wn*32 + n*16 + l15;
      int kc = (s*4 + l4) ^ (r & 7);
      bfr[n] = *(const short8*)(Bs + r*64 + kc*8);
    }
    #pragma unroll
    for (int m = 0; m < 2; m++)
      #pragma unroll
      for (int n = 0; n < 2; n++)
        acc[m][n] = __builtin_amdgcn_mfma_f32_16x16x32_bf16(af[m], bfr[n], acc[m][n], 0, 0, 0);
  }

  #pragma unroll
  for (int m = 0; m < 2; m++) {
    int rr = row0 + wm*32 + m*16 + l4*4;
    #pragma unroll
    for (int n = 0; n < 2; n++) {
      int cc = col0 + wn*32 + n*16 + l15;
      #pragma unroll
      for (int j = 0; j < 4; j++)
        C[(long)(rr + j)*512 + cc] = __float2bfloat16(acc[m][n][j]);
    }
  }
}

// =====================================================================
// Fused attention: QK^T + rel-pos gathers + mask + online softmax + PV.
// Block: 256 thr = 4 waves. 32 q-rows; wave (wq,wk): q-strip wq*16, k-parity wk.
// Each parity pair walks its 4 of 8 k-tiles with private (m,l,out); merged
// through LDS at the end. rel-pos idx: lut[q-k+512] (c2p and p2c share it).
// =====================================================================
__global__ __launch_bounds__(256)
void fused_attn_kernel(const bf16* __restrict__ qkvc, const bf16* __restrict__ vbT,
                       const bf16* __restrict__ c2p, const bf16* __restrict__ p2c,
                       const short* __restrict__ lutG, const float* __restrict__ maskadd,
                       bf16* __restrict__ ctx, int bBase)
{
  __shared__ __align__(16) bf16 Qs[32*64];       // 4 KB
  __shared__ __align__(16) bf16 Ks[2][64*64];    // 16 KB (merge scratch alias)
  __shared__ __align__(16) bf16 Vs[2][64*64];    // 16 KB
  __shared__ __align__(16) bf16 Ps[4][16*64];    // 8 KB
  __shared__ short lutS[1024];                   // 2 KB

  const float SCALE = 0.07216878364870322f;      // 1/sqrt(64*3)
  const int tid = threadIdx.x;
  const int wid = tid >> 6, lane = tid & 63;
  const int wq = wid & 1, wk = wid >> 1;
  const int l15 = lane & 15, l4 = lane >> 4;
  const int bh = blockIdx.y;
  const int tb = bBase + bh / Hh, hh = bh % Hh;
  const int q0b = blockIdx.x * 32;

  const bf16* Qg = qkvc + ((long)tb*Ss)*Dd + hh*DHh;
  const bf16* Kg = qkvc + (long)MRo*Dd + ((long)tb*Ss)*Dd + hh*DHh;
  const bf16* Vt = vbT + ((long)(tb*Hh + hh)*DHh)*Ss;   // [64 dh][512 s]
  const bf16* c2ps = c2p + (long)bh*Ss*Pp;
  const bf16* p2cs = p2c + (long)bh*Ss*Pp;

  // ---- stage Q tile (32x64, swizzled) + LUT ----
  {
    int byteoff = tid*16;
    int r = byteoff >> 7, c = (byteoff >> 4) & 7, kc = c ^ (r & 7);
    __builtin_amdgcn_global_load_lds(
        (const __attribute__((address_space(1))) void*)(Qg + (long)(q0b + r)*Dd + kc*8),
        (__attribute__((address_space(3))) void*)(Qs + wid*512), 16, 0, 0);
  }
  #pragma unroll
  for (int i = 0; i < 4; i++) lutS[tid + i*256] = lutG[tid + i*256];

  float4v out[4];
  float m[4], lsum[4];
  #pragma unroll
  for (int n = 0; n < 4; n++)
    #pragma unroll
    for (int q = 0; q < 4; q++) out[n][q] = 0.f;
  #pragma unroll
  for (int j = 0; j < 4; j++) { m[j] = -1e30f; lsum[j] = 0.f; }

  for (int t = 0; t < 4; t++) {
    // ---- stage K,V tiles for both parities ----
    #pragma unroll
    for (int p = 0; p < 2; p++) {
      int k0 = (t*2 + p)*64;
      #pragma unroll
      for (int i = 0; i < 2; i++) {
        int byteoff = i*4096 + tid*16;
        int r = byteoff >> 7, c = (byteoff >> 4) & 7, kc = c ^ (r & 7);
        __builtin_amdgcn_global_load_lds(
            (const __attribute__((address_space(1))) void*)(Kg + (long)(k0 + r)*Dd + kc*8),
            (__attribute__((address_space(3))) void*)(Ks[p] + i*2048 + wid*512), 16, 0, 0);
        __builtin_amdgcn_global_load_lds(
            (const __attribute__((address_space(1))) void*)(Vt + (long)r*Ss + (k0 + kc*8)),
            (__attribute__((address_space(3))) void*)(Vs[p] + i*2048 + wid*512), 16, 0, 0);
      }
    }
    __syncthreads();

    const int kbase = (t*2 + wk)*64;

    // ---- S = Q @ K^T (16 q-rows x 64 k-cols per wave) ----
    float4v s4[4];
    #pragma unroll
    for (int n = 0; n < 4; n++)
      #pragma unroll
      for (int q = 0; q < 4; q++) s4[n][q] = 0.f;
    #pragma unroll
    for (int s = 0; s < 2; s++) {
      int qrow = wq*16 + l15;
      short8 af = *(const short8*)(Qs + qrow*64 + (((s*4 + l4) ^ (qrow & 7))*8));
      #pragma unroll
      for (int n = 0; n < 4; n++) {
        int krow = n*16 + l15;
        short8 bf8 = *(const short8*)(Ks[wk] + krow*64 + (((s*4 + l4) ^ (krow & 7))*8));
        s4[n] = __builtin_amdgcn_mfma_f32_16x16x32_bf16(af, bf8, s4[n], 0, 0, 0);
      }
    }

    // ---- gathers + scale + mask ----
    float sv[4][4];
    #pragma unroll
    for (int n = 0; n < 4; n++) {
      int kcol = kbase + n*16 + l15;
      float mk = maskadd[tb*Ss + kcol];
      #pragma unroll
      for (int j = 0; j < 4; j++) {
        int q = q0b + wq*16 + l4*4 + j;
        int idx = lutS[q - kcol + 512];
        float c2v = __bfloat162float(c2ps[((long)q << 9) + idx]);
        float p2v = __bfloat162float(p2cs[((long)kcol << 9) + idx]);
        sv[n][j] = (s4[n][j] + c2v + p2v)*SCALE + mk;
      }
    }

    // ---- online softmax (row groups share l4; reduce over l15) ----
    float f[4];
    #pragma unroll
    for (int j = 0; j < 4; j++) {
      float v = fmaxf(fmaxf(sv[0][j], sv[1][j]), fmaxf(sv[2][j], sv[3][j]));
      #pragma unroll
      for (int o = 1; o < 16; o <<= 1) v = fmaxf(v, __shfl_xor(v, o, 64));
      float mn = fmaxf(m[j], v);
      f[j] = __expf(m[j] - mn);
      m[j] = mn;
    }
    float pv[4][4], ts[4] = {0.f, 0.f, 0.f, 0.f};
    #pragma unroll
    for (int n = 0; n < 4; n++)
      #pragma unroll
      for (int j = 0; j < 4; j++) {
        pv[n][j] = __expf(sv[n][j] - m[j]);
        ts[j] += pv[n][j];
      }
    #pragma unroll
    for (int j = 0; j < 4; j++) {
      float v = ts[j];
      #pragma unroll
      for (int o = 1; o < 16; o <<= 1) v += __shfl_xor(v, o, 64);
      lsum[j] = lsum[j]*f[j] + v;
    }
    #pragma unroll
    for (int n = 0; n < 4; n++)
      #pragma unroll
      for (int j = 0; j < 4; j++) out[n][j] *= f[j];

    // ---- P -> LDS (swizzled), then PV ----
    bf16* Pw = Ps[wid];
    #pragma unroll
    for (int n = 0; n < 4; n++)
      #pragma unroll
      for (int j = 0; j < 4; j++) {
        int row = l4*4 + j, col = n*16 + l15;
        Pw[row*64 + (((col >> 3) ^ (row & 7))*8) + (col & 7)] = __float2bfloat16(pv[n][j]);
      }
    #pragma unroll
    for (int s = 0; s < 2; s++) {
      short8 pa = *(const short8*)(Ps[wid] + l15*64 + (((s*4 + l4) ^ (l15 & 7))*8));
      #pragma unroll
      for (int n = 0; n < 4; n++) {
        int vrow = n*16 + l15;
        short8 vb8 = *(const short8*)(Vs[wk] + vrow*64 + (((s*4 + l4) ^ (vrow & 7))*8));
        out[n] = __builtin_amdgcn_mfma_f32_16x16x32_bf16(pa, vb8, out[n], 0, 0, 0);
      }
    }
    __syncthreads();
  }

  // ---- merge k-parity pairs through LDS (alias over Ks) ----
  float* og = (float*)Ks;            // [2][16][64]
  float* mM = og + 2048;             // [2][16]
  float* mL = mM + 32;               // [2][16]
  if (wk == 1) {
    #pragma unroll
    for (int n = 0; n < 4; n++)
      #pragma unroll
      for (int j = 0; j < 4; j++)
        og[wq*1024 + (l4*4 + j)*64 + n*16 + l15] = out[n][j];
    if (l15 == 0)
      #pragma unroll
      for (int j = 0; j < 4; j++) {
        mM[wq*16 + l4*4 + j] = m[j];
        mL[wq*16 + l4*4 + j] = lsum[j];
      }
  }
  __syncthreads();
  if (wk == 0) {
    #pragma unroll
    for (int j = 0; j < 4; j++) {
      int row = l4*4 + j;
      float mB = mM[wq*16 + row], lB = mL[wq*16 + row];
      float M  = fmaxf(m[j], mB);
      float fa = __expf(m[j] - M), fb = __expf(mB - M);
      float invL = 1.0f / (lsum[j]*fa + lB*fb);
      #pragma unroll
      for (int n = 0; n < 4; n++) {
        float v = (out[n][j]*fa + og[wq*1024 + row*64 + n*16 + l15]*fb) * invL;
        ctx[((long)(tb*Ss + q0b + wq*16 + row))*Dd + hh*DHh + n*16 + l15] = __float2bfloat16(v);
      }
    }
  }
}

// ---------------- weight transpose-convert: W[K,N](raw) -> WT[N,K] bf16 ----
__global__ __launch_bounds__(256)
void wtrans_kernel(const void* __restrict__ W0, const void* __restrict__ W1p,
                   const void* __restrict__ W2p, bf16* __restrict__ WT,
                   int Kd, int Nd, long woff, const int* __restrict__ flag)
{
  const int isb = *flag;
  const void* W = blockIdx.z == 0 ? W0 : (blockIdx.z == 1 ? W1p : W2p);
  bf16* T = WT + (long)blockIdx.z * Kd * Nd;
  __shared__ float s[64][65];
  const int n0 = blockIdx.x*64, k0 = blockIdx.y*64;
  const int tc = (threadIdx.x & 15)*4;
  const int tr = threadIdx.x >> 4;
  #pragma unroll
  for (int i = 0; i < 4; i++) {
    int kk = tr + i*16;
    long base = woff + (long)(k0 + kk)*Nd + n0 + tc;
    #pragma unroll
    for (int j = 0; j < 4; j++) s[kk][tc + j] = ldf(W, base + j, isb);
  }
  __syncthreads();
  #pragma unroll
  for (int i = 0; i < 4; i++) {
    int nn = tr + i*16;
    long base = (long)(n0 + nn)*Kd + k0 + tc;
    #pragma unroll
    for (int j = 0; j < 4; j++) T[base + j] = __float2bfloat16(s[tc + j][nn]);
  }
}

// ---------------- V transpose: vb[2048,768] -> vbT[b,h,dh,s] bf16 ----------
__global__ __launch_bounds__(256)
void vtrans_kernel(const bf16* __restrict__ vb, bf16* __restrict__ vbT)
{
  __shared__ float s[64][65];
  const int s0 = blockIdx.x*64, hh = blockIdx.y, b = blockIdx.z;
  const bf16* src = vb + (long)b*Ss*Dd + hh*DHh;
  bf16* dst = vbT + ((long)(b*Hh + hh)*DHh)*Ss;
  const int tc = (threadIdx.x & 15)*4;
  const int tr = threadIdx.x >> 4;
  #pragma unroll
  for (int i = 0; i < 4; i++) {
    int row = tr + i*16;
    long base = (long)(s0 + row)*Dd + tc;
    #pragma unroll
    for (int j = 0; j < 4; j++) s[row][tc + j] = __bfloat162float(src[base + j]);
  }
  __syncthreads();
  #pragma unroll
  for (int i = 0; i < 4; i++) {
    int dh = tr + i*16;
    long base = (long)dh*Ss + s0 + tc;
    #pragma unroll
    for (int j = 0; j < 4; j++) dst[base + j] = __float2bfloat16(s[tc + j][dh]);
  }
}

// ---------------- embedding + LN + mask (writes f32 h and bf16 mirror) ----
__global__ __launch_bounds__(256)
void embed_ln_kernel(const int* __restrict__ ids, const int* __restrict__ segs,
                     const int* __restrict__ pins, const void* __restrict__ mask,
                     const void* __restrict__ tok, const void* __restrict__ pin,
                     const void* __restrict__ seg, const void* __restrict__ lnw,
                     const void* __restrict__ lnb, float* __restrict__ h,
                     bf16* __restrict__ hb, float* __restrict__ maskadd,
                     const int* __restrict__ flag)
{
  __shared__ float red[4];
  const int isb = *flag;
  int t = blockIdx.x;
  long to = (long)ids[t]*Dd, po = (long)pins[t]*Dd, so = (long)segs[t]*Dd;
  float e[3]; float s = 0.f;
  #pragma unroll
  for (int i = 0; i < 3; i++) {
    int d = threadIdx.x + i*256;
    e[i] = ldf(tok, to+d, isb) + ldf(pin, po+d, isb) + ldf(seg, so+d, isb);
    s += e[i];
  }
  float mu = block_sum(s, red) * (1.0f/Dd);
  float vs = 0.f;
  #pragma unroll
  for (int i = 0; i < 3; i++) { float d0 = e[i]-mu; vs += d0*d0; }
  float var = block_sum(vs, red) * (1.0f/Dd);
  float inv = 1.0f / sqrtf(var + 1e-12f);
  float mv = ldf(mask, t, isb);
  #pragma unroll
  for (int i = 0; i < 3; i++) {
    int d = threadIdx.x + i*256;
    float v = ((e[i]-mu)*inv*ldf(lnw, d, isb) + ldf(lnb, d, isb)) * mv;
    h[(long)t*Dd + d]  = v;
    hb[(long)t*Dd + d] = __float2bfloat16(v);
  }
  if (threadIdx.x == 0) maskadd[t] = (1.0f - mv) * (-1e9f);
}

// ---------------- residual add + LN (f32 h in place + bf16 mirror) --------
__global__ __launch_bounds__(256)
void add_ln_kernel(float* __restrict__ h, const float* __restrict__ addv,
                   const void* __restrict__ w, const void* __restrict__ b,
                   long off, const int* __restrict__ flag, bf16* __restrict__ hb)
{
  __shared__ float red[4];
  const int isb = *flag;
  int t = blockIdx.x;
  float e[3]; float s = 0.f;
  #pragma unroll
  for (int i = 0; i < 3; i++) {
    int d = threadIdx.x + i*256;
    e[i] = h[(long)t*Dd + d] + addv[(long)t*Dd + d];
    s += e[i];
  }
  float mu = block_sum(s, red) * (1.0f/Dd);
  float vs = 0.f;
  #pragma unroll
  for (int i = 0; i < 3; i++) { float d0 = e[i]-mu; vs += d0*d0; }
  float var = block_sum(vs, red) * (1.0f/Dd);
  float inv = 1.0f / sqrtf(var + 1e-12f);
  #pragma unroll
  for (int i = 0; i < 3; i++) {
    int d = threadIdx.x + i*256;
    float v = (e[i]-mu)*inv*ldf(w, off+d, isb) + ldf(b, off+d, isb);
    h[(long)t*Dd + d]  = v;
    hb[(long)t*Dd + d] = __float2bfloat16(v);
  }
}

// ---------------- DeBERTa-v2 log-bucket LUT: idx(rel) for rel=q-k ---------
__global__ void bucketlut_kernel(short* __restrict__ lut)
{
  int e = blockIdx.x*256 + threadIdx.x;
  if (e >= 1024) return;
  int rel = e - 512;
  const int mid = 128;
  int sgn = (rel > 0) - (rel < 0);
  int abs_pos = (rel < mid && rel > -mid) ? (mid - 1) : abs(rel);
  int bucket;
  if (abs_pos <= mid) bucket = rel;
  else {
    double lp = ceil(log((double)abs_pos / (double)mid) / log(511.0/128.0) * (double)(mid-1)) + (double)mid;
    bucket = (int)(lp * (double)sgn);
  }
  int ci = bucket + 256;  ci = ci < 0 ? 0 : (ci > 511 ? 511 : ci);
  lut[e] = (short)ci;
}

// ---------------- converts ----------------
__global__ void cvt_in_kernel(const void* __restrict__ in, float* __restrict__ out,
                              const int* __restrict__ flag, int n){
  int i = blockIdx.x*256 + threadIdx.x;
  if (i < n) out[i] = ldf(in, i, *flag);
}
__global__ void cvt_bf16_kernel(const void* __restrict__ in, bf16* __restrict__ out,
                                const int* __restrict__ flag, int n){
  int i = blockIdx.x*256 + threadIdx.x;
  if (i < n) out[i] = __float2bfloat16(ldf(in, i, *flag));
}
__global__ void store_out_kernel(const float* __restrict__ in, void* __restrict__ out,
                                 const int* __restrict__ flag, int n){
  int i = blockIdx.x*256 + threadIdx.x;
  if (i < n) {
    if (*flag) ((bf16*)out)[i] = __float2bfloat16(in[i]);
    else       ((float*)out)[i] = in[i];
  }
}

extern "C" void kernel_launch(void* const* d_in, const int* in_sizes, int n_in,
                              void* d_out, int out_size, void* d_ws, size_t ws_size,
                              hipStream_t stream)
{
  const int*  input_ids   = (const int*) d_in[0];
  const int*  segment_ids = (const int*) d_in[1];
  const int*  pinyin_ids  = (const int*) d_in[2];
  const void* attn_mask   = d_in[3];
  const void* tok_emb     = d_in[4];
  const void* pin_emb     = d_in[5];
  const void* seg_emb     = d_in[6];
  const void* emb_ln_w    = d_in[7];
  const void* emb_ln_b    = d_in[8];
  const void* rel_emb     = d_in[9];
  const void* Wq = d_in[10]; const void* bq = d_in[11];
  const void* Wk = d_in[12]; const void* bk = d_in[13];
  const void* Wv = d_in[14]; const void* bv = d_in[15];
  const void* Wo = d_in[16]; const void* bo = d_in[17];
  const void* ln1w = d_in[18]; const void* ln1b = d_in[19];
  const void* W1 = d_in[20]; const void* b1 = d_in[21];
  const void* W2 = d_in[22]; const void* b2 = d_in[23];
  const void* ln2w = d_in[24]; const void* ln2b = d_in[25];

  // ---- workspace layout. c2p/p2c are bf16 and sized for nb batches per
  // group; pick the largest nb in {4,2,1} that fits ws_size. ----
  float *h, *tmp, *madd, *biasb;
  short *lutG; int *dflag;
  bf16 *c2pb, *p2cb, *hrel, *qkvc, *ctxb, *vbT, *WTb;
  auto build = [&](int nb_) -> size_t {
    float* ws = (float*)d_ws;
    h     = ws;
    tmp   = h    + (long)BSs*Dd;
    madd  = tmp  + (long)BSs*Dd;
    biasb = madd + BSs;
    lutG  = (short*)(biasb + 82944);
    dflag = (int*)(lutG + 1024);                 // lut 2 KB, then flags
    c2pb  = (bf16*)(dflag + 64);
    p2cb  = c2pb + (long)nb_*Hh*Ss*Pp;           // contiguous after c2pb (ffb spans both)
    hrel  = p2cb + (long)nb_*Hh*Ss*Pp;
    qkvc  = hrel + (long)MRo*Dd;
    ctxb  = qkvc + 3L*MRo*Dd;
    vbT   = ctxb + (long)BSs*Dd;
    WTb   = vbT  + (long)BHh*DHh*Ss;
    bf16* end = WTb + (long)Ff*Dd;
    return (size_t)((char*)end - (char*)d_ws);
  };
  int nb = Bb;
  if (build(4) > ws_size) { if (build(2) > ws_size) { nb = 1; build(1); } else nb = 2; }
  const int nbh = nb * Hh;
  bf16* ffb = (bf16*)c2pb;   // alias: c2p+p2c region (>=12.58 MB) dead during FFN

  const bf16* vbs = qkvc + (long)2*MRo*Dd;       // V slab rows 0..2047

  sniff_kernel<<<1, 64, 0, stream>>>((const unsigned*)attn_mask, dflag);
  bucketlut_kernel<<<4, 256, 0, stream>>>(lutG);
  cvt_bf16_kernel<<<(Pp*Dd + 255)/256, 256, 0, stream>>>(rel_emb, hrel + (long)BSs*Dd, dflag, Pp*Dd);
  embed_ln_kernel<<<BSs, 256, 0, stream>>>(input_ids, segment_ids, pinyin_ids, attn_mask,
                                           tok_emb, pin_emb, seg_emb, emb_ln_w, emb_ln_b,
                                           h, hrel, madd, dflag);
  // biases -> f32: bq@0 bk@9216 bv@18432 bo@27648 b1@36864 b2@73728
  int nbia = Ll*Dd;
  cvt_in_kernel<<<(nbia+255)/256, 256, 0, stream>>>(bq, biasb,         dflag, nbia);
  cvt_in_kernel<<<(nbia+255)/256, 256, 0, stream>>>(bk, biasb + 9216,  dflag, nbia);
  cvt_in_kernel<<<(nbia+255)/256, 256, 0, stream>>>(bv, biasb + 18432, dflag, nbia);
  cvt_in_kernel<<<(nbia+255)/256, 256, 0, stream>>>(bo, biasb + 27648, dflag, nbia);
  cvt_in_kernel<<<(Ll*Ff+255)/256, 256, 0, stream>>>(b1, biasb + 36864, dflag, Ll*Ff);
  cvt_in_kernel<<<(nbia+255)/256, 256, 0, stream>>>(b2, biasb + 73728, dflag, nbia);

  for (int l = 0; l < Ll; l++) {
    long oW  = (long)l*Dd*Dd, oW1 = (long)l*Dd*Ff, oW2 = (long)l*Ff*Dd;

    // ---- Wq,Wk,Wv -> WTb [3][768][768] bf16 (transposed) ----
    wtrans_kernel<<<dim3(12,12,3), 256, 0, stream>>>(Wq, Wk, Wv, WTb, Dd, Dd, oW, dflag);
    // ---- fused QKV + pos projections: A=[h||rel] (2560 rows), z = q/k/v ----
    mgemm_kernel<4,4,1,1><<<dim3(Dd/128, MRo/128, 3), 256, 0, stream>>>(
        hrel, WTb, qkvc, biasb + (long)l*Dd,
        Dd, Dd, Dd, Dd, 0L, (long)Dd*Dd, (long)MRo*Dd, 9216);
    // ---- V -> vbT[b,h,dh,s] ----
    vtrans_kernel<<<dim3(Ss/64, Hh, Bb), 256, 0, stream>>>(vbs, vbT);

    // ---- attention in groups of nb batches ----
    for (int g = 0; g < Bb/nb; g++) {
      int bBase = g*nb;
      scores_kernel<<<dim3(Pp/64, Ss/64, 2*nbh), 256, 0, stream>>>(
          qkvc, c2pb, p2cb, nbh, (long)bBase*Ss*Dd);
      fused_attn_kernel<<<dim3(Ss/32, nbh), 256, 0, stream>>>(
          qkvc, vbT, c2pb, p2cb, lutG, madd, ctxb, bBase);
    }

    // ---- Wo ----
    wtrans_kernel<<<dim3(12,12,1), 256, 0, stream>>>(Wo, Wo, Wo, WTb, Dd, Dd, oW, dflag);
    mgemm_kernel<2,2,1,0><<<dim3(Dd/64, BSs/64, 1), 256, 0, stream>>>(
        ctxb, WTb, tmp, biasb + 27648 + (long)l*Dd, Dd, Dd, Dd, Dd, 0L, 0L, 0L, 0);
    add_ln_kernel<<<BSs, 256, 0, stream>>>(h, tmp, ln1w, ln1b, (long)l*Dd, dflag, hrel);

    // ---- FFN ----
    wtrans_kernel<<<dim3(Ff/64, Dd/64, 1), 256, 0, stream>>>(W1, W1, W1, WTb, Dd, Ff, oW1, dflag);
    mgemm_kernel<4,4,2,1><<<dim3(Ff/128, BSs/128, 1), 256, 0, stream>>>(
        hrel, WTb, ffb, biasb + 36864 + (long)l*Ff, Dd, Dd, Dd, Ff, 0L, 0L, 0L, 0);
    wtrans_kernel<<<dim3(Dd/64, Ff/64, 1), 256, 0, stream>>>(W2, W2, W2, WTb, Ff, Dd, oW2, dflag);
    mgemm_kernel<2,2,1,0><<<dim3(Dd/64, BSs/64, 1), 256, 0, stream>>>(
        ffb, WTb, tmp, biasb + 73728 + (long)l*Dd, Ff, Ff, Ff, Dd, 0L, 0L, 0L, 0);
    add_ln_kernel<<<BSs, 256, 0, stream>>>(h, tmp, ln2w, ln2b, (long)l*Dd, dflag, hrel);
  }

  store_out_kernel<<<(BSs*Dd + 255)/256, 256, 0, stream>>>(h, d_out, dflag, BSs*Dd);
}